// Round 5
// baseline (3711.737 us; speedup 1.0000x reference)
//
#include <hip/hip_runtime.h>
#include <hip/hip_bf16.h>

#define S_LEN 2048
#define D_MODEL 1024
#define NH 16
#define DHEAD 64
#define NB 2
#define BI 16
#define BJ 32
#define KRW 48

__device__ __forceinline__ float bf2f(unsigned short u) {
    return __uint_as_float(((unsigned)u) << 16);
}
__device__ __forceinline__ unsigned short f2bf(float f) {
    unsigned x = __float_as_uint(f);
    x += 0x7fffu + ((x >> 16) & 1u);
    return (unsigned short)(x >> 16);
}

// C = A[M,K] @ W[K,N] + bias, K=N=1024. External tensors fp32, internal ws bf16.
// MODE 0: A = internal bf16 (attn), C = fp32 d_out, flat [M,N].
// MODE 1: A = fp32, C = bf16 ws, out[((b*H+h)*S+s)*64+dh].
// MODE 2: A = fp32, C = bf16 ws, out[(h*S+s)*64+dh].
template<int MODE>
__global__ __launch_bounds__(256)
void gemm_bias(const void* __restrict__ A,
               const float* __restrict__ W,
               const float* __restrict__ Bv,
               void* __restrict__ C, int M) {
    const int K = D_MODEL, N = D_MODEL;
    __shared__ float As[32][36];
    __shared__ float Ws[32][36];
    int tid = threadIdx.x;
    int m0 = blockIdx.y * 32;
    int n0 = blockIdx.x * 32;
    int tx = tid & 31, ty = tid >> 5;
    int sr = tid >> 3, sc = (tid & 7) * 4;
    float acc[4] = {0.f, 0.f, 0.f, 0.f};
    for (int k0 = 0; k0 < K; k0 += 32) {
        if (MODE != 0) {
            float4 a4 = *reinterpret_cast<const float4*>((const float*)A + (size_t)(m0 + sr) * K + k0 + sc);
            As[sr][sc + 0] = a4.x; As[sr][sc + 1] = a4.y;
            As[sr][sc + 2] = a4.z; As[sr][sc + 3] = a4.w;
        } else {
            ushort4 a4 = *reinterpret_cast<const ushort4*>((const unsigned short*)A + (size_t)(m0 + sr) * K + k0 + sc);
            As[sr][sc + 0] = bf2f(a4.x); As[sr][sc + 1] = bf2f(a4.y);
            As[sr][sc + 2] = bf2f(a4.z); As[sr][sc + 3] = bf2f(a4.w);
        }
        {
            float4 w4 = *reinterpret_cast<const float4*>(W + (size_t)(k0 + sr) * N + n0 + sc);
            Ws[sr][sc + 0] = w4.x; Ws[sr][sc + 1] = w4.y;
            Ws[sr][sc + 2] = w4.z; Ws[sr][sc + 3] = w4.w;
        }
        __syncthreads();
        #pragma unroll
        for (int kk = 0; kk < 32; ++kk) {
            float wv = Ws[kk][tx];
            acc[0] += As[ty     ][kk] * wv;
            acc[1] += As[ty +  8][kk] * wv;
            acc[2] += As[ty + 16][kk] * wv;
            acc[3] += As[ty + 24][kk] * wv;
        }
        __syncthreads();
    }
    int n = n0 + tx;
    float bv = Bv[n];
    #pragma unroll
    for (int rr = 0; rr < 4; ++rr) {
        int m = m0 + ty + rr * 8;
        float v = acc[rr] + bv;
        if (MODE == 0) {
            ((float*)C)[(size_t)m * N + n] = v;
        } else if (MODE == 1) {
            int b = m >> 11, s = m & 2047, hh = n >> 6, dd = n & 63;
            ((unsigned short*)C)[(((size_t)(b * NH + hh)) * S_LEN + s) * DHEAD + dd] = f2bf(v);
        } else {
            int s = m, hh = n >> 6, dd = n & 63;
            ((unsigned short*)C)[(((size_t)hh) * S_LEN + s) * DHEAD + dd] = f2bf(v);
        }
    }
}

// out[idx] = sum_d uv[h][d] * kmat[grp][pos][d], idx = grp*S + pos, h = grp & 15
// uv fp32 (external), kmat bf16 (internal ws).
__global__ __launch_bounds__(256)
void ef_gh_kernel(const float* __restrict__ uv,
                  const unsigned short* __restrict__ kmat,
                  float* __restrict__ out, int total) {
    int idx = blockIdx.x * 256 + threadIdx.x;
    if (idx >= total) return;
    int pos = idx & (S_LEN - 1);
    int grp = idx >> 11;
    int hh = grp & (NH - 1);
    const unsigned short* krow = kmat + ((size_t)grp * S_LEN + pos) * DHEAD;
    const float* urow = uv + hh * DHEAD;
    float s = 0.f;
    #pragma unroll
    for (int d4 = 0; d4 < DHEAD; d4 += 4) {
        ushort4 kk = *reinterpret_cast<const ushort4*>(krow + d4);
        float4 uu = *reinterpret_cast<const float4*>(urow + d4);
        s += bf2f(kk.x) * uu.x + bf2f(kk.y) * uu.y
           + bf2f(kk.z) * uu.z + bf2f(kk.w) * uu.w;
    }
    out[idx] = s;
}

// Flash-style attention with relative-shift BD term. One block = 16 query rows of one (b,h).
__global__ __launch_bounds__(256)
void flash_kernel(const unsigned short* __restrict__ qT,
                  const unsigned short* __restrict__ kT,
                  const unsigned short* __restrict__ vT,
                  const unsigned short* __restrict__ krT,
                  const float* __restrict__ EF,
                  const float* __restrict__ GH,
                  unsigned short* __restrict__ attn) {
    __shared__ float q_s[BI + 1][68];
    __shared__ float k_s[BJ][68];
    __shared__ float v_s[BJ][68];
    __shared__ float krA_s[KRW][68];
    __shared__ float krB_s[KRW][68];
    __shared__ float p_s[BI][BJ];
    __shared__ float m_s[BI], l_s[BI], f_s[BI];

    int tid = threadIdx.x;
    int bid = blockIdx.x;
    int ib = bid & 127;            // S/BI = 128
    int bh = bid >> 7;             // 0..31
    int h = bh & (NH - 1);
    int i0 = ib * BI;

    const unsigned short* qbase = qT + (size_t)bh * S_LEN * DHEAD;
    const unsigned short* kbase = kT + (size_t)bh * S_LEN * DHEAD;
    const unsigned short* vbase = vT + (size_t)bh * S_LEN * DHEAD;
    const unsigned short* krbase = krT + (size_t)h * S_LEN * DHEAD;
    const float* efrow = EF + (size_t)bh * S_LEN;
    const float* ghrow = GH + (size_t)h * S_LEN;

    // stage Q rows i0 .. i0+16 (17 rows; row 16 feeds the "wrap junk" BD region)
    for (int slot = tid; slot < (BI + 1) * 16; slot += 256) {
        int r = slot >> 4, c4 = (slot & 15) * 4;
        int gi = i0 + r;
        float4 vals;
        if (gi < S_LEN) {
            ushort4 u4 = *reinterpret_cast<const ushort4*>(qbase + (size_t)gi * DHEAD + c4);
            vals = make_float4(bf2f(u4.x), bf2f(u4.y), bf2f(u4.z), bf2f(u4.w));
        } else {
            vals = make_float4(0.f, 0.f, 0.f, 0.f);
        }
        q_s[r][c4 + 0] = vals.x; q_s[r][c4 + 1] = vals.y;
        q_s[r][c4 + 2] = vals.z; q_s[r][c4 + 3] = vals.w;
    }
    if (tid < BI) { m_s[tid] = -1e30f; l_s[tid] = 0.f; f_s[tid] = 0.f; }
    float o0 = 0.f, o1 = 0.f, o2 = 0.f, o3 = 0.f;
    int dlane = tid & 63;
    int pg = tid >> 6;   // PV rows: pg*4 + rr
    __syncthreads();

    for (int jt = 0; jt < S_LEN / BJ; ++jt) {
        int j0 = jt * BJ;
        for (int slot = tid; slot < BJ * 16; slot += 256) {
            int r = slot >> 4, c4 = (slot & 15) * 4;
            size_t off = (size_t)(j0 + r) * DHEAD + c4;
            ushort4 ku = *reinterpret_cast<const ushort4*>(kbase + off);
            ushort4 vu = *reinterpret_cast<const ushort4*>(vbase + off);
            k_s[r][c4 + 0] = bf2f(ku.x); k_s[r][c4 + 1] = bf2f(ku.y);
            k_s[r][c4 + 2] = bf2f(ku.z); k_s[r][c4 + 3] = bf2f(ku.w);
            v_s[r][c4 + 0] = bf2f(vu.x); v_s[r][c4 + 1] = bf2f(vu.y);
            v_s[r][c4 + 2] = bf2f(vu.z); v_s[r][c4 + 3] = bf2f(vu.w);
        }
        bool activeA = (j0 <= i0 + BI - 1);
        int lA0 = S_LEN - 1 + j0 - i0 - (BI - 1);
        if (activeA) {
            for (int slot = tid; slot < KRW * 16; slot += 256) {
                int r = slot >> 4, c4 = (slot & 15) * 4;
                int l = lA0 + r;
                if (l >= 0 && l < S_LEN) {
                    ushort4 u4 = *reinterpret_cast<const ushort4*>(krbase + (size_t)l * DHEAD + c4);
                    krA_s[r][c4 + 0] = bf2f(u4.x); krA_s[r][c4 + 1] = bf2f(u4.y);
                    krA_s[r][c4 + 2] = bf2f(u4.z); krA_s[r][c4 + 3] = bf2f(u4.w);
                } else {
                    krA_s[r][c4 + 0] = 0.f; krA_s[r][c4 + 1] = 0.f;
                    krA_s[r][c4 + 2] = 0.f; krA_s[r][c4 + 3] = 0.f;
                }
            }
        }
        bool activeB = (j0 + BJ - 1 >= i0 + 2);
        int lB0 = j0 - i0 - (BI + 1);
        if (activeB) {
            for (int slot = tid; slot < KRW * 16; slot += 256) {
                int r = slot >> 4, c4 = (slot & 15) * 4;
                int l = lB0 + r;
                if (l >= 0 && l < S_LEN) {
                    ushort4 u4 = *reinterpret_cast<const ushort4*>(krbase + (size_t)l * DHEAD + c4);
                    krB_s[r][c4 + 0] = bf2f(u4.x); krB_s[r][c4 + 1] = bf2f(u4.y);
                    krB_s[r][c4 + 2] = bf2f(u4.z); krB_s[r][c4 + 3] = bf2f(u4.w);
                } else {
                    krB_s[r][c4 + 0] = 0.f; krB_s[r][c4 + 1] = 0.f;
                    krB_s[r][c4 + 2] = 0.f; krB_s[r][c4 + 3] = 0.f;
                }
            }
        }
        __syncthreads();

        // scores -> p_s (logits)
        {
            int jl = tid & 31;
            int g = tid >> 5;
            int j = j0 + jl;
            float efv = efrow[j];
            #pragma unroll
            for (int rr = 0; rr < 2; ++rr) {
                int il = g * 2 + rr;
                int i = i0 + il;
                float ac = 0.f;
                #pragma unroll
                for (int d = 0; d < DHEAD; ++d) ac += q_s[il][d] * k_s[jl][d];
                float bd = 0.f;
                if (j <= i) {
                    int wi = jl + (BI - 1) - il;            // l - lA0
                    #pragma unroll
                    for (int d = 0; d < DHEAD; ++d) bd += q_s[il][d] * krA_s[wi][d];
                } else if (j > i + 1) {
                    int wi = jl - il + (BI - 1);            // (j-i-2) - lB0
                    #pragma unroll
                    for (int d = 0; d < DHEAD; ++d) bd += q_s[il + 1][d] * krB_s[wi][d];
                }
                p_s[il][jl] = (ac + bd + efv + ghrow[i]) * 0.125f;
            }
        }
        __syncthreads();

        // online softmax update
        {
            int row = tid >> 4;
            int sub = tid & 15;
            float s1 = p_s[row][sub];
            float s2 = p_s[row][sub + 16];
            float tmax = fmaxf(s1, s2);
            #pragma unroll
            for (int off = 8; off >= 1; off >>= 1) tmax = fmaxf(tmax, __shfl_xor(tmax, off));
            float mold = m_s[row];
            float mnew = fmaxf(mold, tmax);
            float p1 = __expf(s1 - mnew);
            float p2 = __expf(s2 - mnew);
            p_s[row][sub] = p1;
            p_s[row][sub + 16] = p2;
            float psum = p1 + p2;
            #pragma unroll
            for (int off = 8; off >= 1; off >>= 1) psum += __shfl_xor(psum, off);
            if (sub == 0) {
                float f = __expf(mold - mnew);
                l_s[row] = l_s[row] * f + psum;
                m_s[row] = mnew;
                f_s[row] = f;
            }
        }
        __syncthreads();

        // PV accumulate
        {
            o0 *= f_s[pg * 4 + 0];
            o1 *= f_s[pg * 4 + 1];
            o2 *= f_s[pg * 4 + 2];
            o3 *= f_s[pg * 4 + 3];
            #pragma unroll 8
            for (int j = 0; j < BJ; ++j) {
                float vv = v_s[j][dlane];
                o0 += p_s[pg * 4 + 0][j] * vv;
                o1 += p_s[pg * 4 + 1][j] * vv;
                o2 += p_s[pg * 4 + 2][j] * vv;
                o3 += p_s[pg * 4 + 3][j] * vv;
            }
        }
        __syncthreads();
    }

    // epilogue: normalize, write attn[b][i][h*64+d] (bf16 ws, [B,S,D] layout)
    int b = bh >> 4;
    float outs[4] = {o0, o1, o2, o3};
    #pragma unroll
    for (int rr = 0; rr < 4; ++rr) {
        int il = pg * 4 + rr;
        int i = i0 + il;
        float v = outs[rr] / l_s[il];
        attn[((size_t)b * S_LEN + i) * D_MODEL + h * DHEAD + dlane] = f2bf(v);
    }
}

extern "C" void kernel_launch(void* const* d_in, const int* in_sizes, int n_in,
                              void* d_out, int out_size, void* d_ws, size_t ws_size,
                              hipStream_t stream) {
    const float* x    = (const float*)d_in[0];
    const float* pos  = (const float*)d_in[1];
    const float* Wq   = (const float*)d_in[2];
    const float* bq   = (const float*)d_in[3];
    const float* Wk   = (const float*)d_in[4];
    const float* bk   = (const float*)d_in[5];
    const float* Wv   = (const float*)d_in[6];
    const float* bv   = (const float*)d_in[7];
    const float* Wo   = (const float*)d_in[8];
    const float* bo   = (const float*)d_in[9];
    const float* Wkr  = (const float*)d_in[10];
    const float* bkr  = (const float*)d_in[11];
    const float* uu   = (const float*)d_in[12];
    const float* vv   = (const float*)d_in[13];

    char* w = (char*)d_ws;
    unsigned short* qT   = (unsigned short*)(w);                  // 8 MB
    unsigned short* kT   = (unsigned short*)(w + 8388608);        // 8 MB
    unsigned short* vT   = (unsigned short*)(w + 16777216);       // 8 MB
    unsigned short* krT  = (unsigned short*)(w + 25165824);       // 4 MB
    unsigned short* attn = (unsigned short*)(w + 29360128);       // 8 MB
    float* EF = (float*)(w + 37748736);                           // 256 KB
    float* GH = (float*)(w + 38273024);                           // 128 KB

    dim3 blk(256);
    dim3 g1(32, 128);   // N/32, M/32 for M=4096
    dim3 g2(32, 64);    // M=2048

    gemm_bias<1><<<g1, blk, 0, stream>>>(x, Wq, bq, qT, 4096);
    gemm_bias<1><<<g1, blk, 0, stream>>>(x, Wk, bk, kT, 4096);
    gemm_bias<1><<<g1, blk, 0, stream>>>(x, Wv, bv, vT, 4096);
    gemm_bias<2><<<g2, blk, 0, stream>>>(pos, Wkr, bkr, krT, 2048);

    ef_gh_kernel<<<(NB * NH * S_LEN) / 256, blk, 0, stream>>>(uu, kT, EF, NB * NH * S_LEN);
    ef_gh_kernel<<<(NH * S_LEN) / 256, blk, 0, stream>>>(vv, krT, GH, NH * S_LEN);

    flash_kernel<<<NB * NH * (S_LEN / BI), blk, 0, stream>>>(qT, kT, vT, krT, EF, GH, attn);

    gemm_bias<0><<<g1, blk, 0, stream>>>(attn, Wo, bo, (float*)d_out, 4096);
}

// Round 7
// 2800.611 us; speedup vs baseline: 1.3253x; 1.3253x over previous
//
#include <hip/hip_runtime.h>
#include <hip/hip_bf16.h>

#define S_LEN 2048
#define D_MODEL 1024
#define NH 16
#define DHEAD 64
#define NB 2

typedef __attribute__((ext_vector_type(8))) short bf16x8;
typedef __attribute__((ext_vector_type(4))) float f32x4;

__device__ __forceinline__ float bf2f(unsigned short u) {
    return __uint_as_float(((unsigned)u) << 16);
}
__device__ __forceinline__ unsigned short f2bf(float f) {
    unsigned x = __float_as_uint(f);
    x += 0x7fffu + ((x >> 16) & 1u);
    return (unsigned short)(x >> 16);
}

// fp32 -> bf16 elementwise (n4 = count/4)
__global__ __launch_bounds__(256)
void convert_bf16(const float* __restrict__ in, unsigned short* __restrict__ out, int n4) {
    int i = blockIdx.x * 256 + threadIdx.x;
    if (i >= n4) return;
    float4 v = reinterpret_cast<const float4*>(in)[i];
    ushort4 o;
    o.x = f2bf(v.x); o.y = f2bf(v.y); o.z = f2bf(v.z); o.w = f2bf(v.w);
    reinterpret_cast<ushort4*>(out)[i] = o;
}

// Wt[n][k] = bf16(W[k][n]), 1024x1024
__global__ __launch_bounds__(256)
void convert_transpose(const float* __restrict__ in, unsigned short* __restrict__ out) {
    __shared__ float t[32][33];
    int k0 = blockIdx.y * 32, n0 = blockIdx.x * 32;
    int tx = threadIdx.x & 31, ty = threadIdx.x >> 5;
    #pragma unroll
    for (int r = ty; r < 32; r += 8) t[r][tx] = in[(size_t)(k0 + r) * D_MODEL + n0 + tx];
    __syncthreads();
    #pragma unroll
    for (int r = ty; r < 32; r += 8) out[(size_t)(n0 + r) * D_MODEL + k0 + tx] = f2bf(t[tx][r]);
}

// C = A[M,1024] @ W + bias, via Wt[n][k] bf16. MFMA 16x16x32 bf16.
// MODE 0: C fp32 flat [M,N] (d_out). MODE 1: C bf16 [((b*16+h)*2048+s)*64+dh].
// MODE 2: C bf16 [(h*2048+s)*64+dh].
template<int MODE>
__global__ __launch_bounds__(256)
void gemm_mfma(const unsigned short* __restrict__ A,
               const unsigned short* __restrict__ Wt,
               const float* __restrict__ bias,
               void* __restrict__ C, int M) {
    const int K = D_MODEL;
    __shared__ short As[128][72];
    __shared__ short Bs[128][72];
    int tid = threadIdx.x;
    int m0 = blockIdx.y * 128, n0 = blockIdx.x * 128;
    int lane = tid & 63, w = tid >> 6;
    int wm = (w >> 1) * 64, wn = (w & 1) * 64;
    int ls = lane & 15, lg = lane >> 4;

    f32x4 acc[4][4];
    #pragma unroll
    for (int ms = 0; ms < 4; ++ms)
        #pragma unroll
        for (int ns = 0; ns < 4; ++ns)
            acc[ms][ns] = (f32x4){0.f, 0.f, 0.f, 0.f};

    for (int k0 = 0; k0 < K; k0 += 64) {
        // stage 128 rows x 64 cols for A and B: 1024 chunks of 8 bf16 each
        #pragma unroll
        for (int it = 0; it < 4; ++it) {
            int id = tid + it * 256;
            int row = id >> 3, ch = (id & 7) * 8;
            *reinterpret_cast<bf16x8*>(&As[row][ch]) =
                *reinterpret_cast<const bf16x8*>(A + (size_t)(m0 + row) * K + k0 + ch);
            *reinterpret_cast<bf16x8*>(&Bs[row][ch]) =
                *reinterpret_cast<const bf16x8*>(Wt + (size_t)(n0 + row) * K + k0 + ch);
        }
        __syncthreads();
        #pragma unroll
        for (int kk = 0; kk < 64; kk += 32) {
            bf16x8 af[4], bf[4];
            #pragma unroll
            for (int s = 0; s < 4; ++s) {
                af[s] = *reinterpret_cast<const bf16x8*>(&As[wm + s * 16 + ls][kk + lg * 8]);
                bf[s] = *reinterpret_cast<const bf16x8*>(&Bs[wn + s * 16 + ls][kk + lg * 8]);
            }
            #pragma unroll
            for (int ms = 0; ms < 4; ++ms)
                #pragma unroll
                for (int ns = 0; ns < 4; ++ns)
                    acc[ms][ns] = __builtin_amdgcn_mfma_f32_16x16x32_bf16(af[ms], bf[ns], acc[ms][ns], 0, 0, 0);
        }
        __syncthreads();
    }

    #pragma unroll
    for (int ns = 0; ns < 4; ++ns) {
        int n = n0 + wn + ns * 16 + ls;
        float bv = bias[n];
        #pragma unroll
        for (int ms = 0; ms < 4; ++ms) {
            #pragma unroll
            for (int e = 0; e < 4; ++e) {
                int m = m0 + wm + ms * 16 + lg * 4 + e;
                float v = acc[ms][ns][e] + bv;
                if (MODE == 0) {
                    ((float*)C)[(size_t)m * D_MODEL + n] = v;
                } else if (MODE == 1) {
                    int b = m >> 11, s = m & 2047, hh = n >> 6, dd = n & 63;
                    ((unsigned short*)C)[(((size_t)(b * NH + hh)) * S_LEN + s) * DHEAD + dd] = f2bf(v);
                } else {
                    int s = m, hh = n >> 6, dd = n & 63;
                    ((unsigned short*)C)[(((size_t)hh) * S_LEN + s) * DHEAD + dd] = f2bf(v);
                }
            }
        }
    }
}

// out[idx] = sum_d uv[h][d] * kmat[grp][pos][d]
__global__ __launch_bounds__(256)
void ef_gh_kernel(const float* __restrict__ uv,
                  const unsigned short* __restrict__ kmat,
                  float* __restrict__ out, int total) {
    int idx = blockIdx.x * 256 + threadIdx.x;
    if (idx >= total) return;
    int pos = idx & (S_LEN - 1);
    int grp = idx >> 11;
    int hh = grp & (NH - 1);
    const unsigned short* krow = kmat + ((size_t)grp * S_LEN + pos) * DHEAD;
    const float* urow = uv + hh * DHEAD;
    float s = 0.f;
    #pragma unroll
    for (int d4 = 0; d4 < DHEAD; d4 += 4) {
        ushort4 kk = *reinterpret_cast<const ushort4*>(krow + d4);
        float4 uu = *reinterpret_cast<const float4*>(urow + d4);
        s += bf2f(kk.x) * uu.x + bf2f(kk.y) * uu.y
           + bf2f(kk.z) * uu.z + bf2f(kk.w) * uu.w;
    }
    out[idx] = s;
}

// Flash attention with relative-shift BD. Block = 16 q-rows of one (b,h); j-tiles of 64.
// Unified KREXT window: KREXT[t] = (t<=0) ? kr[S-1+t] : kr[t-1], t in [j0-i0-16, j0-i0+63].
// BD[i][j] = dot(q_i, KREXT[j-i])        for j<=i    (wi = jl-il+16)
//          = 0                            for j==i+1
//          = dot(q_{i+1}, KREXT[j-i-1])   for j>=i+2  (wi = jl-il+15)
__global__ __launch_bounds__(256)
void flash_kernel(const unsigned short* __restrict__ qT,
                  const unsigned short* __restrict__ kT,
                  const unsigned short* __restrict__ vT,
                  const unsigned short* __restrict__ krT,
                  const float* __restrict__ EF,
                  const float* __restrict__ GH,
                  unsigned short* __restrict__ attn) {
    __shared__ float q_s[17][66];
    __shared__ float k_s[64][66];
    __shared__ float v_s[64][66];
    __shared__ float krx_s[80][66];
    __shared__ float p_s[16][66];
    __shared__ float m_s[16], l_s[16], f_s[16];

    int tid = threadIdx.x;
    int bid = blockIdx.x;
    int ib = bid & 127;
    int bh = bid >> 7;
    int h = bh & (NH - 1);
    int i0 = ib * 16;

    const unsigned short* qbase = qT + (size_t)bh * S_LEN * DHEAD;
    const unsigned short* kbase = kT + (size_t)bh * S_LEN * DHEAD;
    const unsigned short* vbase = vT + (size_t)bh * S_LEN * DHEAD;
    const unsigned short* krbase = krT + (size_t)h * S_LEN * DHEAD;
    const float* efrow = EF + (size_t)bh * S_LEN;
    const float* ghrow = GH + (size_t)h * S_LEN;

    for (int slot = tid; slot < 17 * 16; slot += 256) {
        int r = slot >> 4, c4 = (slot & 15) * 4;
        int gi = i0 + r;
        if (gi < S_LEN) {
            ushort4 u4 = *reinterpret_cast<const ushort4*>(qbase + (size_t)gi * DHEAD + c4);
            q_s[r][c4 + 0] = bf2f(u4.x); q_s[r][c4 + 1] = bf2f(u4.y);
            q_s[r][c4 + 2] = bf2f(u4.z); q_s[r][c4 + 3] = bf2f(u4.w);
        } else {
            q_s[r][c4 + 0] = 0.f; q_s[r][c4 + 1] = 0.f;
            q_s[r][c4 + 2] = 0.f; q_s[r][c4 + 3] = 0.f;
        }
    }
    if (tid < 16) { m_s[tid] = -1e30f; l_s[tid] = 0.f; f_s[tid] = 0.f; }
    float o0 = 0.f, o1 = 0.f, o2 = 0.f, o3 = 0.f;
    int dlane = tid & 63;
    int pg = tid >> 6;
    int jh = tid & 31;
    int rp = tid >> 5;
    int il0 = rp * 2, il1 = rp * 2 + 1;
    __syncthreads();

    for (int jt = 0; jt < S_LEN / 64; ++jt) {
        int j0 = jt * 64;
        for (int slot = tid; slot < 64 * 16; slot += 256) {
            int r = slot >> 4, c4 = (slot & 15) * 4;
            size_t off = (size_t)(j0 + r) * DHEAD + c4;
            ushort4 ku = *reinterpret_cast<const ushort4*>(kbase + off);
            ushort4 vu = *reinterpret_cast<const ushort4*>(vbase + off);
            k_s[r][c4 + 0] = bf2f(ku.x); k_s[r][c4 + 1] = bf2f(ku.y);
            k_s[r][c4 + 2] = bf2f(ku.z); k_s[r][c4 + 3] = bf2f(ku.w);
            v_s[r][c4 + 0] = bf2f(vu.x); v_s[r][c4 + 1] = bf2f(vu.y);
            v_s[r][c4 + 2] = bf2f(vu.z); v_s[r][c4 + 3] = bf2f(vu.w);
        }
        int t_lo = j0 - i0 - 16;
        for (int slot = tid; slot < 80 * 16; slot += 256) {
            int r = slot >> 4, c4 = (slot & 15) * 4;
            int t = t_lo + r;
            int gk = (t <= 0) ? (S_LEN - 1 + t) : (t - 1);
            if (gk >= 0) {
                ushort4 u4 = *reinterpret_cast<const ushort4*>(krbase + (size_t)gk * DHEAD + c4);
                krx_s[r][c4 + 0] = bf2f(u4.x); krx_s[r][c4 + 1] = bf2f(u4.y);
                krx_s[r][c4 + 2] = bf2f(u4.z); krx_s[r][c4 + 3] = bf2f(u4.w);
            } else {
                krx_s[r][c4 + 0] = 0.f; krx_s[r][c4 + 1] = 0.f;
                krx_s[r][c4 + 2] = 0.f; krx_s[r][c4 + 3] = 0.f;
            }
        }
        __syncthreads();

        // scores: 2 rows x 2 cols per thread
        {
            float ac00 = 0.f, ac01 = 0.f, ac10 = 0.f, ac11 = 0.f;
            #pragma unroll 8
            for (int d = 0; d < DHEAD; d += 2) {
                float2 qa = *reinterpret_cast<const float2*>(&q_s[il0][d]);
                float2 qb = *reinterpret_cast<const float2*>(&q_s[il1][d]);
                float2 ka = *reinterpret_cast<const float2*>(&k_s[jh][d]);
                float2 kb = *reinterpret_cast<const float2*>(&k_s[jh + 32][d]);
                ac00 += qa.x * ka.x + qa.y * ka.y;
                ac01 += qa.x * kb.x + qa.y * kb.y;
                ac10 += qb.x * ka.x + qb.y * ka.y;
                ac11 += qb.x * kb.x + qb.y * kb.y;
            }
            float bd[2][2] = {{0.f, 0.f}, {0.f, 0.f}};
            #pragma unroll
            for (int rr = 0; rr < 2; ++rr) {
                int il = rp * 2 + rr;
                int i = i0 + il;
                #pragma unroll
                for (int cc = 0; cc < 2; ++cc) {
                    int jl = jh + cc * 32;
                    int j = j0 + jl;
                    if (j == i + 1) continue;
                    bool caseA = (j <= i);
                    int qrow = caseA ? il : (il + 1);
                    int wi = jl - il + (caseA ? 16 : 15);
                    float s = 0.f;
                    #pragma unroll 8
                    for (int d = 0; d < DHEAD; d += 2) {
                        float2 qv = *reinterpret_cast<const float2*>(&q_s[qrow][d]);
                        float2 kv = *reinterpret_cast<const float2*>(&krx_s[wi][d]);
                        s += qv.x * kv.x + qv.y * kv.y;
                    }
                    bd[rr][cc] = s;
                }
            }
            float ef0 = efrow[j0 + jh], ef1 = efrow[j0 + jh + 32];
            float gh0 = ghrow[i0 + il0], gh1 = ghrow[i0 + il1];
            p_s[il0][jh]      = (ac00 + bd[0][0] + ef0 + gh0) * 0.125f;
            p_s[il0][jh + 32] = (ac01 + bd[0][1] + ef1 + gh0) * 0.125f;
            p_s[il1][jh]      = (ac10 + bd[1][0] + ef0 + gh1) * 0.125f;
            p_s[il1][jh + 32] = (ac11 + bd[1][1] + ef1 + gh1) * 0.125f;
        }
        __syncthreads();

        // online softmax
        {
            int row = tid >> 4, sub = tid & 15;
            float s0 = p_s[row][sub], s1 = p_s[row][sub + 16];
            float s2 = p_s[row][sub + 32], s3 = p_s[row][sub + 48];
            float tmax = fmaxf(fmaxf(s0, s1), fmaxf(s2, s3));
            #pragma unroll
            for (int off = 8; off >= 1; off >>= 1) tmax = fmaxf(tmax, __shfl_xor(tmax, off));
            float mold = m_s[row];
            float mnew = fmaxf(mold, tmax);
            float p0 = __expf(s0 - mnew), p1 = __expf(s1 - mnew);
            float p2 = __expf(s2 - mnew), p3 = __expf(s3 - mnew);
            p_s[row][sub] = p0; p_s[row][sub + 16] = p1;
            p_s[row][sub + 32] = p2; p_s[row][sub + 48] = p3;
            float psum = (p0 + p1) + (p2 + p3);
            #pragma unroll
            for (int off = 8; off >= 1; off >>= 1) psum += __shfl_xor(psum, off);
            if (sub == 0) {
                float f = __expf(mold - mnew);
                l_s[row] = l_s[row] * f + psum;
                m_s[row] = mnew;
                f_s[row] = f;
            }
        }
        __syncthreads();

        // PV
        {
            o0 *= f_s[pg * 4 + 0];
            o1 *= f_s[pg * 4 + 1];
            o2 *= f_s[pg * 4 + 2];
            o3 *= f_s[pg * 4 + 3];
            #pragma unroll 8
            for (int j = 0; j < 64; j += 2) {
                float va = v_s[j][dlane], vb = v_s[j + 1][dlane];
                float2 pa = *reinterpret_cast<const float2*>(&p_s[pg * 4 + 0][j]);
                float2 pb = *reinterpret_cast<const float2*>(&p_s[pg * 4 + 1][j]);
                float2 pc = *reinterpret_cast<const float2*>(&p_s[pg * 4 + 2][j]);
                float2 pd = *reinterpret_cast<const float2*>(&p_s[pg * 4 + 3][j]);
                o0 += pa.x * va + pa.y * vb;
                o1 += pb.x * va + pb.y * vb;
                o2 += pc.x * va + pc.y * vb;
                o3 += pd.x * va + pd.y * vb;
            }
        }
        __syncthreads();
    }

    int b = bh >> 4;
    float outs[4] = {o0, o1, o2, o3};
    #pragma unroll
    for (int rr = 0; rr < 4; ++rr) {
        int il = pg * 4 + rr;
        int i = i0 + il;
        float v = outs[rr] / l_s[il];
        attn[((size_t)b * S_LEN + i) * D_MODEL + h * DHEAD + dlane] = f2bf(v);
    }
}

extern "C" void kernel_launch(void* const* d_in, const int* in_sizes, int n_in,
                              void* d_out, int out_size, void* d_ws, size_t ws_size,
                              hipStream_t stream) {
    const float* x    = (const float*)d_in[0];
    const float* pos  = (const float*)d_in[1];
    const float* Wq   = (const float*)d_in[2];
    const float* bq   = (const float*)d_in[3];
    const float* Wk   = (const float*)d_in[4];
    const float* bk   = (const float*)d_in[5];
    const float* Wv   = (const float*)d_in[6];
    const float* bv   = (const float*)d_in[7];
    const float* Wo   = (const float*)d_in[8];
    const float* bo   = (const float*)d_in[9];
    const float* Wkr  = (const float*)d_in[10];
    const float* bkr  = (const float*)d_in[11];
    const float* uu   = (const float*)d_in[12];
    const float* vv   = (const float*)d_in[13];

    char* w = (char*)d_ws;
    unsigned short* qT   = (unsigned short*)(w);                  // 8 MB
    unsigned short* kT   = (unsigned short*)(w + 8388608);        // 8 MB
    unsigned short* vT   = (unsigned short*)(w + 16777216);       // 8 MB
    unsigned short* krT  = (unsigned short*)(w + 25165824);       // 4 MB
    unsigned short* attn = (unsigned short*)(w + 29360128);       // 8 MB
    float* EF            = (float*)(w + 37748736);                // 256 KB
    float* GH            = (float*)(w + 38010880);                // 128 KB
    unsigned short* xb   = (unsigned short*)(w + 38141952);       // 8 MB
    unsigned short* posb = (unsigned short*)(w + 46530560);       // 4 MB
    unsigned short* Wt   = (unsigned short*)(w + 50724864);       // 2 MB (reused)

    dim3 blk(256);
    dim3 gT(32, 32);
    dim3 gBig(8, 32);   // N/128, 4096/128
    dim3 gSm(8, 16);    // N/128, 2048/128

    convert_bf16<<<4096, blk, 0, stream>>>(x, xb, 1048576);
    convert_bf16<<<2048, blk, 0, stream>>>(pos, posb, 524288);

    convert_transpose<<<gT, blk, 0, stream>>>(Wq, Wt);
    gemm_mfma<1><<<gBig, blk, 0, stream>>>(xb, Wt, bq, qT, 4096);
    convert_transpose<<<gT, blk, 0, stream>>>(Wk, Wt);
    gemm_mfma<1><<<gBig, blk, 0, stream>>>(xb, Wt, bk, kT, 4096);
    convert_transpose<<<gT, blk, 0, stream>>>(Wv, Wt);
    gemm_mfma<1><<<gBig, blk, 0, stream>>>(xb, Wt, bv, vT, 4096);
    convert_transpose<<<gT, blk, 0, stream>>>(Wkr, Wt);
    gemm_mfma<2><<<gSm, blk, 0, stream>>>(posb, Wt, bkr, krT, 2048);

    ef_gh_kernel<<<(NB * NH * S_LEN) / 256, blk, 0, stream>>>(uu, kT, EF, NB * NH * S_LEN);
    ef_gh_kernel<<<(NH * S_LEN) / 256, blk, 0, stream>>>(vv, krT, GH, NH * S_LEN);

    flash_kernel<<<NB * NH * (S_LEN / 16), blk, 0, stream>>>(qT, kT, vT, krT, EF, GH, attn);

    convert_transpose<<<gT, blk, 0, stream>>>(Wo, Wt);
    gemm_mfma<0><<<gBig, blk, 0, stream>>>(attn, Wt, bo, (float*)d_out, 4096);
}

// Round 8
// 979.670 us; speedup vs baseline: 3.7888x; 2.8587x over previous
//
#include <hip/hip_runtime.h>
#include <hip/hip_bf16.h>

#define S_LEN 2048
#define D_MODEL 1024
#define NH 16
#define DHEAD 64
#define NB 2

typedef __attribute__((ext_vector_type(8))) short bf16x8;
typedef __attribute__((ext_vector_type(4))) float f32x4;

__device__ __forceinline__ float bf2f(unsigned short u) {
    return __uint_as_float(((unsigned)u) << 16);
}
__device__ __forceinline__ unsigned short f2bf(float f) {
    unsigned x = __float_as_uint(f);
    x += 0x7fffu + ((x >> 16) & 1u);
    return (unsigned short)(x >> 16);
}

// fp32 -> bf16 elementwise (n4 = count/4)
__global__ __launch_bounds__(256)
void convert_bf16(const float* __restrict__ in, unsigned short* __restrict__ out, int n4) {
    int i = blockIdx.x * 256 + threadIdx.x;
    if (i >= n4) return;
    float4 v = reinterpret_cast<const float4*>(in)[i];
    ushort4 o;
    o.x = f2bf(v.x); o.y = f2bf(v.y); o.z = f2bf(v.z); o.w = f2bf(v.w);
    reinterpret_cast<ushort4*>(out)[i] = o;
}

// Wt[n][k] = bf16(W[k][n]), 1024x1024
__global__ __launch_bounds__(256)
void convert_transpose(const float* __restrict__ in, unsigned short* __restrict__ out) {
    __shared__ float t[32][33];
    int k0 = blockIdx.y * 32, n0 = blockIdx.x * 32;
    int tx = threadIdx.x & 31, ty = threadIdx.x >> 5;
    #pragma unroll
    for (int r = ty; r < 32; r += 8) t[r][tx] = in[(size_t)(k0 + r) * D_MODEL + n0 + tx];
    __syncthreads();
    #pragma unroll
    for (int r = ty; r < 32; r += 8) out[(size_t)(n0 + r) * D_MODEL + k0 + tx] = f2bf(t[tx][r]);
}

// C = A[M,1024] @ W + bias via Wt[n][k] bf16. MFMA 16x16x32 bf16.
template<int MODE>
__global__ __launch_bounds__(256)
void gemm_mfma(const unsigned short* __restrict__ A,
               const unsigned short* __restrict__ Wt,
               const float* __restrict__ bias,
               void* __restrict__ C, int M) {
    const int K = D_MODEL;
    __shared__ short As[128][72];
    __shared__ short Bs[128][72];
    int tid = threadIdx.x;
    int m0 = blockIdx.y * 128, n0 = blockIdx.x * 128;
    int lane = tid & 63, w = tid >> 6;
    int wm = (w >> 1) * 64, wn = (w & 1) * 64;
    int ls = lane & 15, lg = lane >> 4;

    f32x4 acc[4][4];
    #pragma unroll
    for (int ms = 0; ms < 4; ++ms)
        #pragma unroll
        for (int ns = 0; ns < 4; ++ns)
            acc[ms][ns] = (f32x4){0.f, 0.f, 0.f, 0.f};

    for (int k0 = 0; k0 < K; k0 += 64) {
        #pragma unroll
        for (int it = 0; it < 4; ++it) {
            int id = tid + it * 256;
            int row = id >> 3, ch = (id & 7) * 8;
            *reinterpret_cast<bf16x8*>(&As[row][ch]) =
                *reinterpret_cast<const bf16x8*>(A + (size_t)(m0 + row) * K + k0 + ch);
            *reinterpret_cast<bf16x8*>(&Bs[row][ch]) =
                *reinterpret_cast<const bf16x8*>(Wt + (size_t)(n0 + row) * K + k0 + ch);
        }
        __syncthreads();
        #pragma unroll
        for (int kk = 0; kk < 64; kk += 32) {
            bf16x8 af[4], bf[4];
            #pragma unroll
            for (int s = 0; s < 4; ++s) {
                af[s] = *reinterpret_cast<const bf16x8*>(&As[wm + s * 16 + ls][kk + lg * 8]);
                bf[s] = *reinterpret_cast<const bf16x8*>(&Bs[wn + s * 16 + ls][kk + lg * 8]);
            }
            #pragma unroll
            for (int ms = 0; ms < 4; ++ms)
                #pragma unroll
                for (int ns = 0; ns < 4; ++ns)
                    acc[ms][ns] = __builtin_amdgcn_mfma_f32_16x16x32_bf16(af[ms], bf[ns], acc[ms][ns], 0, 0, 0);
        }
        __syncthreads();
    }

    #pragma unroll
    for (int ns = 0; ns < 4; ++ns) {
        int n = n0 + wn + ns * 16 + ls;
        float bv = bias[n];
        #pragma unroll
        for (int ms = 0; ms < 4; ++ms) {
            #pragma unroll
            for (int e = 0; e < 4; ++e) {
                int m = m0 + wm + ms * 16 + lg * 4 + e;
                float v = acc[ms][ns][e] + bv;
                if (MODE == 0) {
                    ((float*)C)[(size_t)m * D_MODEL + n] = v;
                } else if (MODE == 1) {
                    int b = m >> 11, s = m & 2047, hh = n >> 6, dd = n & 63;
                    ((unsigned short*)C)[(((size_t)(b * NH + hh)) * S_LEN + s) * DHEAD + dd] = f2bf(v);
                } else {
                    int s = m, hh = n >> 6, dd = n & 63;
                    ((unsigned short*)C)[(((size_t)hh) * S_LEN + s) * DHEAD + dd] = f2bf(v);
                }
            }
        }
    }
}

// out[idx] = sum_d uv[h][d] * kmat[grp][pos][d]
__global__ __launch_bounds__(256)
void ef_gh_kernel(const float* __restrict__ uv,
                  const unsigned short* __restrict__ kmat,
                  float* __restrict__ out, int total) {
    int idx = blockIdx.x * 256 + threadIdx.x;
    if (idx >= total) return;
    int pos = idx & (S_LEN - 1);
    int grp = idx >> 11;
    int hh = grp & (NH - 1);
    const unsigned short* krow = kmat + ((size_t)grp * S_LEN + pos) * DHEAD;
    const float* urow = uv + hh * DHEAD;
    float s = 0.f;
    #pragma unroll
    for (int d4 = 0; d4 < DHEAD; d4 += 4) {
        ushort4 kk = *reinterpret_cast<const ushort4*>(krow + d4);
        float4 uu = *reinterpret_cast<const float4*>(urow + d4);
        s += bf2f(kk.x) * uu.x + bf2f(kk.y) * uu.y
           + bf2f(kk.z) * uu.z + bf2f(kk.w) * uu.w;
    }
    out[idx] = s;
}

// MFMA flash attention with relative-shift BD via auxiliary D-GEMM.
// Block: 32 q-rows of one (b,h), 2 waves (wave s owns rows 16s..16s+15). j-tiles of 64.
// KRX[u] = KREXT[u + dj - 32], dj=j0-i0, KREXT[t] = t<=0 ? kr[S-1+t] : kr[t-1].
// D[r][u] = q_{i0+r} . KRX[u]  (rows 0..31 MFMA, row 32 VALU by wave 1).
// BD[il][jl]: t=dj+jl-il;  t<=0 -> D[il][jl-il+32];  t==1 -> 0;  t>=2 -> D[il+1][jl-il+31].
__global__ __launch_bounds__(128)
void flash_mfma(const unsigned short* __restrict__ qT,
                const unsigned short* __restrict__ kT,
                const unsigned short* __restrict__ vT,
                const unsigned short* __restrict__ krT,
                const float* __restrict__ EF,
                const float* __restrict__ GH,
                unsigned short* __restrict__ attn) {
    __shared__ unsigned short Qs[33][72];
    __shared__ unsigned short Ks[64][72];
    __shared__ unsigned short Vt[64][72];   // Vt[d][j]
    __shared__ unsigned short KRX[96][72];  // Pb (32x72 bf16) aliases the head of this
    __shared__ float Dl[33][100];
    __shared__ float ef_s[64];
    __shared__ float gh_s[32];

    unsigned short* Pb = &KRX[0][0];        // phase-disjoint alias (see barriers)

    int tid = threadIdx.x;
    int bid = blockIdx.x;
    int ib = bid & 63;             // S/32 = 64 i-tiles
    int bh = bid >> 6;             // 0..31
    int h = bh & (NH - 1);
    int b = bh >> 4;
    int i0 = ib * 32;

    int lane = tid & 63;
    int wv = tid >> 6;             // wave 0/1
    int ls = lane & 15, lg = lane >> 4;

    const unsigned short* qbase = qT + (size_t)bh * S_LEN * DHEAD;
    const unsigned short* kbase = kT + (size_t)bh * S_LEN * DHEAD;
    const unsigned short* vbase = vT + (size_t)bh * S_LEN * DHEAD;
    const unsigned short* krbase = krT + (size_t)h * S_LEN * DHEAD;
    const float* efrow = EF + (size_t)bh * S_LEN;
    const float* ghrow = GH + (size_t)h * S_LEN;

    // ---- stage Q (33 rows; row 32 feeds D's extra row) + gh ----
    for (int c = tid; c < 33 * 8; c += 128) {
        int r = c >> 3, c8 = (c & 7) * 8;
        int gi = i0 + r;
        bf16x8 val = (bf16x8){0, 0, 0, 0, 0, 0, 0, 0};
        if (gi < S_LEN)
            val = *reinterpret_cast<const bf16x8*>(qbase + (size_t)gi * DHEAD + c8);
        *reinterpret_cast<bf16x8*>(&Qs[r][c8]) = val;
    }
    if (tid < 32) gh_s[tid] = ghrow[i0 + tid];
    __syncthreads();

    // hoisted Q A-fragments (row = 16*wv + ls, k = kk + lg*8)
    bf16x8 aq[2];
    #pragma unroll
    for (int kki = 0; kki < 2; ++kki)
        aq[kki] = *reinterpret_cast<const bf16x8*>(&Qs[16 * wv + ls][kki * 32 + lg * 8]);

    f32x4 acc_o[4];
    #pragma unroll
    for (int nt = 0; nt < 4; ++nt) acc_o[nt] = (f32x4){0.f, 0.f, 0.f, 0.f};
    float m_r[4], l_r[4];
    #pragma unroll
    for (int e = 0; e < 4; ++e) { m_r[e] = -1e30f; l_r[e] = 0.f; }

    for (int jt = 0; jt < S_LEN / 64; ++jt) {
        int j0 = jt * 64;
        int dj = j0 - i0;

        // ---- phase 1: stage K, Vt (transposed), KRX, ef ----
        for (int c = tid; c < 64 * 8; c += 128) {
            int r = c >> 3, c8 = (c & 7) * 8;
            *reinterpret_cast<bf16x8*>(&Ks[r][c8]) =
                *reinterpret_cast<const bf16x8*>(kbase + (size_t)(j0 + r) * DHEAD + c8);
        }
        for (int c = tid; c < 64 * 16; c += 128) {
            int r = c >> 4, d0 = (c & 15) * 4;
            ushort4 u4 = *reinterpret_cast<const ushort4*>(vbase + (size_t)(j0 + r) * DHEAD + d0);
            Vt[d0 + 0][r] = u4.x; Vt[d0 + 1][r] = u4.y;
            Vt[d0 + 2][r] = u4.z; Vt[d0 + 3][r] = u4.w;
        }
        for (int c = tid; c < 96 * 8; c += 128) {
            int u = c >> 3, c8 = (c & 7) * 8;
            int t = u + dj - 32;
            int gk = (t <= 0) ? (S_LEN - 1 + t) : (t - 1);
            bf16x8 val = (bf16x8){0, 0, 0, 0, 0, 0, 0, 0};
            if (gk >= 0 && gk < S_LEN)
                val = *reinterpret_cast<const bf16x8*>(krbase + (size_t)gk * DHEAD + c8);
            *reinterpret_cast<bf16x8*>(&KRX[u][c8]) = val;
        }
        if (tid < 64) ef_s[tid] = efrow[j0 + tid];
        __syncthreads();

        // ---- phase 2: AC + BD MFMA, D spill, D row 32 ----
        f32x4 acc_ac[4], acc_bd[6];
        #pragma unroll
        for (int nt = 0; nt < 4; ++nt) acc_ac[nt] = (f32x4){0.f, 0.f, 0.f, 0.f};
        #pragma unroll
        for (int nt = 0; nt < 6; ++nt) acc_bd[nt] = (f32x4){0.f, 0.f, 0.f, 0.f};

        #pragma unroll
        for (int kki = 0; kki < 2; ++kki) {
            #pragma unroll
            for (int nt = 0; nt < 4; ++nt) {
                bf16x8 bk = *reinterpret_cast<const bf16x8*>(&Ks[nt * 16 + ls][kki * 32 + lg * 8]);
                acc_ac[nt] = __builtin_amdgcn_mfma_f32_16x16x32_bf16(aq[kki], bk, acc_ac[nt], 0, 0, 0);
            }
            #pragma unroll
            for (int nt = 0; nt < 6; ++nt) {
                bf16x8 bx = *reinterpret_cast<const bf16x8*>(&KRX[nt * 16 + ls][kki * 32 + lg * 8]);
                acc_bd[nt] = __builtin_amdgcn_mfma_f32_16x16x32_bf16(aq[kki], bx, acc_bd[nt], 0, 0, 0);
            }
        }
        #pragma unroll
        for (int nt = 0; nt < 6; ++nt)
            #pragma unroll
            for (int e = 0; e < 4; ++e)
                Dl[16 * wv + lg * 4 + e][nt * 16 + ls] = acc_bd[nt][e];
        if (wv == 1) {
            // D row 32: q row i0+32 dot KRX[u], u = lane in [0,63]
            float s = 0.f;
            #pragma unroll
            for (int k8 = 0; k8 < 8; ++k8) {
                bf16x8 q8 = *reinterpret_cast<const bf16x8*>(&Qs[32][k8 * 8]);
                bf16x8 x8 = *reinterpret_cast<const bf16x8*>(&KRX[lane][k8 * 8]);
                #pragma unroll
                for (int e = 0; e < 8; ++e)
                    s += bf2f((unsigned short)q8[e]) * bf2f((unsigned short)x8[e]);
            }
            Dl[32][lane] = s;
        }
        __syncthreads();

        // ---- phase 3: assemble logits, register softmax, write Pb (bf16) ----
        float pv[4][4];   // [nt][e]
        #pragma unroll
        for (int nt = 0; nt < 4; ++nt) {
            int jl = nt * 16 + ls;
            float efv = ef_s[jl];
            #pragma unroll
            for (int e = 0; e < 4; ++e) {
                int il = 16 * wv + lg * 4 + e;
                int t = dj + jl - il;
                float bd;
                if (t == 1)      bd = 0.f;
                else if (t <= 0) bd = Dl[il][jl - il + 32];
                else             bd = Dl[il + 1][jl - il + 31];
                pv[nt][e] = (acc_ac[nt][e] + bd + efv + gh_s[il]) * 0.125f;
            }
        }
        float fr[4];
        #pragma unroll
        for (int e = 0; e < 4; ++e) {
            float tm = fmaxf(fmaxf(pv[0][e], pv[1][e]), fmaxf(pv[2][e], pv[3][e]));
            #pragma unroll
            for (int off = 8; off >= 1; off >>= 1) tm = fmaxf(tm, __shfl_xor(tm, off));
            float mnew = fmaxf(m_r[e], tm);
            float fe = __expf(m_r[e] - mnew);
            float rs = 0.f;
            #pragma unroll
            for (int nt = 0; nt < 4; ++nt) {
                pv[nt][e] = __expf(pv[nt][e] - mnew);
                rs += pv[nt][e];
            }
            #pragma unroll
            for (int off = 8; off >= 1; off >>= 1) rs += __shfl_xor(rs, off);
            l_r[e] = l_r[e] * fe + rs;
            m_r[e] = mnew;
            fr[e] = fe;
        }
        #pragma unroll
        for (int nt = 0; nt < 4; ++nt)
            #pragma unroll
            for (int e = 0; e < 4; ++e)
                Pb[(16 * wv + lg * 4 + e) * 72 + nt * 16 + ls] = f2bf(pv[nt][e]);
        __syncthreads();

        // ---- phase 4: PV MFMA (rescale O, accumulate) ----
        #pragma unroll
        for (int nt = 0; nt < 4; ++nt)
            #pragma unroll
            for (int e = 0; e < 4; ++e)
                acc_o[nt][e] *= fr[e];
        #pragma unroll
        for (int kki = 0; kki < 2; ++kki) {
            bf16x8 ap = *reinterpret_cast<const bf16x8*>(&Pb[(16 * wv + ls) * 72 + kki * 32 + lg * 8]);
            #pragma unroll
            for (int nt = 0; nt < 4; ++nt) {
                bf16x8 bv = *reinterpret_cast<const bf16x8*>(&Vt[nt * 16 + ls][kki * 32 + lg * 8]);
                acc_o[nt] = __builtin_amdgcn_mfma_f32_16x16x32_bf16(ap, bv, acc_o[nt], 0, 0, 0);
            }
        }
        __syncthreads();
    }

    // epilogue: O/l -> attn[b][i0+il][h*64+d]
    #pragma unroll
    for (int nt = 0; nt < 4; ++nt) {
        int d = nt * 16 + ls;
        #pragma unroll
        for (int e = 0; e < 4; ++e) {
            int il = 16 * wv + lg * 4 + e;
            float v = acc_o[nt][e] / l_r[e];
            attn[((size_t)b * S_LEN + i0 + il) * D_MODEL + h * DHEAD + d] = f2bf(v);
        }
    }
}

extern "C" void kernel_launch(void* const* d_in, const int* in_sizes, int n_in,
                              void* d_out, int out_size, void* d_ws, size_t ws_size,
                              hipStream_t stream) {
    const float* x    = (const float*)d_in[0];
    const float* pos  = (const float*)d_in[1];
    const float* Wq   = (const float*)d_in[2];
    const float* bq   = (const float*)d_in[3];
    const float* Wk   = (const float*)d_in[4];
    const float* bk   = (const float*)d_in[5];
    const float* Wv   = (const float*)d_in[6];
    const float* bv   = (const float*)d_in[7];
    const float* Wo   = (const float*)d_in[8];
    const float* bo   = (const float*)d_in[9];
    const float* Wkr  = (const float*)d_in[10];
    const float* bkr  = (const float*)d_in[11];
    const float* uu   = (const float*)d_in[12];
    const float* vv   = (const float*)d_in[13];

    char* w = (char*)d_ws;
    unsigned short* qT   = (unsigned short*)(w);                  // 8 MB
    unsigned short* kT   = (unsigned short*)(w + 8388608);        // 8 MB
    unsigned short* vT   = (unsigned short*)(w + 16777216);       // 8 MB
    unsigned short* krT  = (unsigned short*)(w + 25165824);       // 4 MB
    unsigned short* attn = (unsigned short*)(w + 29360128);       // 8 MB
    float* EF            = (float*)(w + 37748736);                // 256 KB
    float* GH            = (float*)(w + 38010880);                // 128 KB
    unsigned short* xb   = (unsigned short*)(w + 38141952);       // 8 MB
    unsigned short* posb = (unsigned short*)(w + 46530560);       // 4 MB
    unsigned short* Wt   = (unsigned short*)(w + 50724864);       // 2 MB (reused)

    dim3 blk(256);
    dim3 gT(32, 32);
    dim3 gBig(8, 32);   // N/128, 4096/128
    dim3 gSm(8, 16);    // N/128, 2048/128

    convert_bf16<<<4096, blk, 0, stream>>>(x, xb, 1048576);
    convert_bf16<<<2048, blk, 0, stream>>>(pos, posb, 524288);

    convert_transpose<<<gT, blk, 0, stream>>>(Wq, Wt);
    gemm_mfma<1><<<gBig, blk, 0, stream>>>(xb, Wt, bq, qT, 4096);
    convert_transpose<<<gT, blk, 0, stream>>>(Wk, Wt);
    gemm_mfma<1><<<gBig, blk, 0, stream>>>(xb, Wt, bk, kT, 4096);
    convert_transpose<<<gT, blk, 0, stream>>>(Wv, Wt);
    gemm_mfma<1><<<gBig, blk, 0, stream>>>(xb, Wt, bv, vT, 4096);
    convert_transpose<<<gT, blk, 0, stream>>>(Wkr, Wt);
    gemm_mfma<2><<<gSm, blk, 0, stream>>>(posb, Wt, bkr, krT, 2048);

    ef_gh_kernel<<<(NB * NH * S_LEN) / 256, blk, 0, stream>>>(uu, kT, EF, NB * NH * S_LEN);
    ef_gh_kernel<<<(NH * S_LEN) / 256, blk, 0, stream>>>(vv, krT, GH, NH * S_LEN);

    flash_mfma<<<NB * NH * (S_LEN / 32), dim3(128), 0, stream>>>(qT, kT, vT, krT, EF, GH, attn);

    convert_transpose<<<gT, blk, 0, stream>>>(Wo, Wt);
    gemm_mfma<0><<<gBig, blk, 0, stream>>>(attn, Wt, bo, (float*)d_out, 4096);
}

// Round 9
// 585.327 us; speedup vs baseline: 6.3413x; 1.6737x over previous
//
#include <hip/hip_runtime.h>
#include <hip/hip_bf16.h>

#define S_LEN 2048
#define D_MODEL 1024
#define NH 16
#define DHEAD 64
#define NB 2

typedef __attribute__((ext_vector_type(8))) short bf16x8;
typedef __attribute__((ext_vector_type(4))) float f32x4;

__device__ __forceinline__ float bf2f(unsigned short u) {
    return __uint_as_float(((unsigned)u) << 16);
}
__device__ __forceinline__ unsigned short f2bf(float f) {
    unsigned x = __float_as_uint(f);
    x += 0x7fffu + ((x >> 16) & 1u);
    return (unsigned short)(x >> 16);
}

// fp32 -> bf16 elementwise (n4 = count/4)
__global__ __launch_bounds__(256)
void convert_bf16(const float* __restrict__ in, unsigned short* __restrict__ out, int n4) {
    int i = blockIdx.x * 256 + threadIdx.x;
    if (i >= n4) return;
    float4 v = reinterpret_cast<const float4*>(in)[i];
    ushort4 o;
    o.x = f2bf(v.x); o.y = f2bf(v.y); o.z = f2bf(v.z); o.w = f2bf(v.w);
    reinterpret_cast<ushort4*>(out)[i] = o;
}

// Wt[n][k] = bf16(W[k][n]), 1024x1024
__global__ __launch_bounds__(256)
void convert_transpose(const float* __restrict__ in, unsigned short* __restrict__ out) {
    __shared__ float t[32][33];
    int k0 = blockIdx.y * 32, n0 = blockIdx.x * 32;
    int tx = threadIdx.x & 31, ty = threadIdx.x >> 5;
    #pragma unroll
    for (int r = ty; r < 32; r += 8) t[r][tx] = in[(size_t)(k0 + r) * D_MODEL + n0 + tx];
    __syncthreads();
    #pragma unroll
    for (int r = ty; r < 32; r += 8) out[(size_t)(n0 + r) * D_MODEL + k0 + tx] = f2bf(t[tx][r]);
}

// C = A[M,1024] @ W + bias via Wt[n][k] bf16. MFMA 16x16x32 bf16.
// MODE 0: fp32 flat [M,N]. MODE 1: bf16 [bh][s][dh]. MODE 2: bf16 [h][s][dh].
// MODE 3: bf16 TRANSPOSED [bh][dh][s]  (for V).
template<int MODE>
__global__ __launch_bounds__(256)
void gemm_mfma(const unsigned short* __restrict__ A,
               const unsigned short* __restrict__ Wt,
               const float* __restrict__ bias,
               void* __restrict__ C, int M) {
    const int K = D_MODEL;
    __shared__ short As[128][72];
    __shared__ short Bs[128][72];
    int tid = threadIdx.x;
    int m0 = blockIdx.y * 128, n0 = blockIdx.x * 128;
    int lane = tid & 63, w = tid >> 6;
    int wm = (w >> 1) * 64, wn = (w & 1) * 64;
    int ls = lane & 15, lg = lane >> 4;

    f32x4 acc[4][4];
    #pragma unroll
    for (int ms = 0; ms < 4; ++ms)
        #pragma unroll
        for (int ns = 0; ns < 4; ++ns)
            acc[ms][ns] = (f32x4){0.f, 0.f, 0.f, 0.f};

    for (int k0 = 0; k0 < K; k0 += 64) {
        #pragma unroll
        for (int it = 0; it < 4; ++it) {
            int id = tid + it * 256;
            int row = id >> 3, ch = (id & 7) * 8;
            *reinterpret_cast<bf16x8*>(&As[row][ch]) =
                *reinterpret_cast<const bf16x8*>(A + (size_t)(m0 + row) * K + k0 + ch);
            *reinterpret_cast<bf16x8*>(&Bs[row][ch]) =
                *reinterpret_cast<const bf16x8*>(Wt + (size_t)(n0 + row) * K + k0 + ch);
        }
        __syncthreads();
        #pragma unroll
        for (int kk = 0; kk < 64; kk += 32) {
            bf16x8 af[4], bf[4];
            #pragma unroll
            for (int s = 0; s < 4; ++s) {
                af[s] = *reinterpret_cast<const bf16x8*>(&As[wm + s * 16 + ls][kk + lg * 8]);
                bf[s] = *reinterpret_cast<const bf16x8*>(&Bs[wn + s * 16 + ls][kk + lg * 8]);
            }
            #pragma unroll
            for (int ms = 0; ms < 4; ++ms)
                #pragma unroll
                for (int ns = 0; ns < 4; ++ns)
                    acc[ms][ns] = __builtin_amdgcn_mfma_f32_16x16x32_bf16(af[ms], bf[ns], acc[ms][ns], 0, 0, 0);
        }
        __syncthreads();
    }

    #pragma unroll
    for (int ns = 0; ns < 4; ++ns) {
        int n = n0 + wn + ns * 16 + ls;
        float bv = bias[n];
        #pragma unroll
        for (int ms = 0; ms < 4; ++ms) {
            #pragma unroll
            for (int e = 0; e < 4; ++e) {
                int m = m0 + wm + ms * 16 + lg * 4 + e;
                float v = acc[ms][ns][e] + bv;
                if (MODE == 0) {
                    ((float*)C)[(size_t)m * D_MODEL + n] = v;
                } else if (MODE == 1) {
                    int b = m >> 11, s = m & 2047, hh = n >> 6, dd = n & 63;
                    ((unsigned short*)C)[(((size_t)(b * NH + hh)) * S_LEN + s) * DHEAD + dd] = f2bf(v);
                } else if (MODE == 2) {
                    int s = m, hh = n >> 6, dd = n & 63;
                    ((unsigned short*)C)[(((size_t)hh) * S_LEN + s) * DHEAD + dd] = f2bf(v);
                } else {
                    int b = m >> 11, s = m & 2047, hh = n >> 6, dd = n & 63;
                    ((unsigned short*)C)[(((size_t)(b * NH + hh)) * DHEAD + dd) * S_LEN + s] = f2bf(v);
                }
            }
        }
    }
}

// out[idx] = sum_d uv[h][d] * kmat[grp][pos][d]
__global__ __launch_bounds__(256)
void ef_gh_kernel(const float* __restrict__ uv,
                  const unsigned short* __restrict__ kmat,
                  float* __restrict__ out, int total) {
    int idx = blockIdx.x * 256 + threadIdx.x;
    if (idx >= total) return;
    int pos = idx & (S_LEN - 1);
    int grp = idx >> 11;
    int hh = grp & (NH - 1);
    const unsigned short* krow = kmat + ((size_t)grp * S_LEN + pos) * DHEAD;
    const float* urow = uv + hh * DHEAD;
    float s = 0.f;
    #pragma unroll
    for (int d4 = 0; d4 < DHEAD; d4 += 4) {
        ushort4 kk = *reinterpret_cast<const ushort4*>(krow + d4);
        float4 uu = *reinterpret_cast<const float4*>(urow + d4);
        s += bf2f(kk.x) * uu.x + bf2f(kk.y) * uu.y
           + bf2f(kk.z) * uu.z + bf2f(kk.w) * uu.w;
    }
    out[idx] = s;
}

// MFMA flash attention, 64 q-rows per block, 4 waves (wave w owns rows 16w..16w+15).
// Unified KRXU[v] = KREXT[v + dj - 64], dj = j0-i0; KREXT[t] = t<=0 ? kr[S-1+t] : kr[t-1].
// Toeplitz-packed D: Dp[r][c] = q_{i0+r} . KREXT[(j0+c)-(i0+r)]  (c = 0..63).
//   BD[il][jl]: t=dj+jl-il;  t<=0 -> Dp[il][jl];  t==1 -> 0;  t>=2 -> Dp[il+1][jl].
// D-MFMA: wave w computes its 16 rows over v-tiles nt = 3-w .. 7-w (band cover), spills band.
// Row 64 of Dp: VALU dot by wave 3 (q row i0+64 from Qs64).
__global__ __launch_bounds__(256, 3)
void flash_mfma(const unsigned short* __restrict__ qT,
                const unsigned short* __restrict__ kT,
                const unsigned short* __restrict__ vTt,   // [bh][d][s]
                const unsigned short* __restrict__ krT,
                const float* __restrict__ EF,
                const float* __restrict__ GH,
                unsigned short* __restrict__ attn) {
    __shared__ unsigned short Ks[64][72];
    __shared__ unsigned short Vt[64][72];     // Vt[d][j]
    __shared__ unsigned short KRXU[128][72];  // Pb (64x72) aliases rows 0..63 (phase-disjoint)
    __shared__ unsigned short Dp[65][68];     // bf16 packed-D
    __shared__ unsigned short Qs64[72];
    __shared__ float ef_s[64];
    __shared__ float gh_s[64];

    unsigned short* Pb = &KRXU[0][0];

    int tid = threadIdx.x;
    int bid = blockIdx.x;
    int ib = bid & 31;             // S/64 = 32 i-tiles
    int bh = bid >> 5;             // 0..31
    int h = bh & (NH - 1);
    int b = bh >> 4;
    int i0 = ib * 64;

    int lane = tid & 63;
    int w = tid >> 6;              // wave 0..3
    int ls = lane & 15, lg = lane >> 4;

    const unsigned short* qbase = qT + (size_t)bh * S_LEN * DHEAD;
    const unsigned short* kbase = kT + (size_t)bh * S_LEN * DHEAD;
    const unsigned short* vtbase = vTt + (size_t)bh * DHEAD * S_LEN;
    const unsigned short* krbase = krT + (size_t)h * S_LEN * DHEAD;
    const float* efrow = EF + (size_t)bh * S_LEN;
    const float* ghrow = GH + (size_t)h * S_LEN;

    if (tid < 64) gh_s[tid] = ghrow[i0 + tid];
    if (tid < 8) {
        bf16x8 val = (bf16x8){0, 0, 0, 0, 0, 0, 0, 0};
        if (i0 + 64 < S_LEN)
            val = *reinterpret_cast<const bf16x8*>(qbase + (size_t)(i0 + 64) * DHEAD + tid * 8);
        *reinterpret_cast<bf16x8*>(&Qs64[tid * 8]) = val;
    }

    // Q fragments in registers (A-frag: row = 16w+ls, k = kki*32+lg*8)
    bf16x8 aq[2];
    #pragma unroll
    for (int kki = 0; kki < 2; ++kki)
        aq[kki] = *reinterpret_cast<const bf16x8*>(qbase + (size_t)(i0 + 16 * w + ls) * DHEAD + kki * 32 + lg * 8);

    f32x4 acc_o[4];
    #pragma unroll
    for (int nt = 0; nt < 4; ++nt) acc_o[nt] = (f32x4){0.f, 0.f, 0.f, 0.f};
    float m_r[4], l_r[4];
    #pragma unroll
    for (int e = 0; e < 4; ++e) { m_r[e] = -1e30f; l_r[e] = 0.f; }

    int nt0 = 3 - w;

    for (int jt = 0; jt < S_LEN / 64; ++jt) {
        int j0 = jt * 64;
        int dj = j0 - i0;

        // ---- phase 1: stage Ks, Vt (from pre-transposed global), KRXU, ef ----
        #pragma unroll
        for (int it = 0; it < 2; ++it) {
            int s2 = tid + it * 256;
            int r = s2 >> 3, c8 = (s2 & 7) * 8;
            *reinterpret_cast<bf16x8*>(&Ks[r][c8]) =
                *reinterpret_cast<const bf16x8*>(kbase + (size_t)(j0 + r) * DHEAD + c8);
            *reinterpret_cast<bf16x8*>(&Vt[r][c8]) =
                *reinterpret_cast<const bf16x8*>(vtbase + (size_t)r * S_LEN + j0 + c8);
        }
        #pragma unroll
        for (int it = 0; it < 4; ++it) {
            int s2 = tid + it * 256;
            int v = s2 >> 3, c8 = (s2 & 7) * 8;
            int t = v + dj - 64;
            int gk = (t <= 0) ? (S_LEN - 1 + t) : (t - 1);
            bf16x8 val = (bf16x8){0, 0, 0, 0, 0, 0, 0, 0};
            if (gk >= 0)
                val = *reinterpret_cast<const bf16x8*>(krbase + (size_t)gk * DHEAD + c8);
            *reinterpret_cast<bf16x8*>(&KRXU[v][c8]) = val;
        }
        if (tid < 64) ef_s[tid] = efrow[j0 + tid];
        __syncthreads();

        // ---- phase 2: AC + banded-D MFMA, Dp spill, Dp row 64 ----
        f32x4 acc_ac[4];
        f32x4 acc_bd[5];
        #pragma unroll
        for (int nt = 0; nt < 4; ++nt) acc_ac[nt] = (f32x4){0.f, 0.f, 0.f, 0.f};
        #pragma unroll
        for (int i = 0; i < 5; ++i) acc_bd[i] = (f32x4){0.f, 0.f, 0.f, 0.f};

        #pragma unroll
        for (int kki = 0; kki < 2; ++kki) {
            #pragma unroll
            for (int nt = 0; nt < 4; ++nt) {
                bf16x8 bk = *reinterpret_cast<const bf16x8*>(&Ks[nt * 16 + ls][kki * 32 + lg * 8]);
                acc_ac[nt] = __builtin_amdgcn_mfma_f32_16x16x32_bf16(aq[kki], bk, acc_ac[nt], 0, 0, 0);
            }
            #pragma unroll
            for (int i = 0; i < 5; ++i) {
                bf16x8 bx = *reinterpret_cast<const bf16x8*>(&KRXU[(nt0 + i) * 16 + ls][kki * 32 + lg * 8]);
                acc_bd[i] = __builtin_amdgcn_mfma_f32_16x16x32_bf16(aq[kki], bx, acc_bd[i], 0, 0, 0);
            }
        }
        #pragma unroll
        for (int i = 0; i < 5; ++i) {
            int v = (nt0 + i) * 16 + ls;
            #pragma unroll
            for (int e = 0; e < 4; ++e) {
                int r = 16 * w + lg * 4 + e;
                int c = v + r - 64;
                if ((unsigned)c < 64u) Dp[r][c] = f2bf(acc_bd[i][e]);
            }
        }
        if (w == 3) {
            float s = 0.f;
            #pragma unroll
            for (int k8 = 0; k8 < 8; ++k8) {
                bf16x8 q8 = *reinterpret_cast<const bf16x8*>(&Qs64[k8 * 8]);
                bf16x8 x8 = *reinterpret_cast<const bf16x8*>(&KRXU[lane][k8 * 8]);
                #pragma unroll
                for (int e = 0; e < 8; ++e)
                    s += bf2f((unsigned short)q8[e]) * bf2f((unsigned short)x8[e]);
            }
            Dp[64][lane] = f2bf(s);
        }
        __syncthreads();

        // ---- phase 3: logits, register online-softmax, write Pb ----
        float pv[4][4];
        #pragma unroll
        for (int nt = 0; nt < 4; ++nt) {
            int jl = nt * 16 + ls;
            float efv = ef_s[jl];
            #pragma unroll
            for (int e = 0; e < 4; ++e) {
                int il = 16 * w + lg * 4 + e;
                int t = dj + jl - il;
                float bd = (t == 1) ? 0.f : (t <= 0 ? bf2f(Dp[il][jl]) : bf2f(Dp[il + 1][jl]));
                pv[nt][e] = (acc_ac[nt][e] + bd + efv + gh_s[il]) * 0.125f;
            }
        }
        float fr[4];
        #pragma unroll
        for (int e = 0; e < 4; ++e) {
            float tm = fmaxf(fmaxf(pv[0][e], pv[1][e]), fmaxf(pv[2][e], pv[3][e]));
            #pragma unroll
            for (int off = 8; off >= 1; off >>= 1) tm = fmaxf(tm, __shfl_xor(tm, off));
            float mnew = fmaxf(m_r[e], tm);
            float fe = __expf(m_r[e] - mnew);
            float rs = 0.f;
            #pragma unroll
            for (int nt = 0; nt < 4; ++nt) {
                pv[nt][e] = __expf(pv[nt][e] - mnew);
                rs += pv[nt][e];
            }
            #pragma unroll
            for (int off = 8; off >= 1; off >>= 1) rs += __shfl_xor(rs, off);
            l_r[e] = l_r[e] * fe + rs;
            m_r[e] = mnew;
            fr[e] = fe;
        }
        #pragma unroll
        for (int nt = 0; nt < 4; ++nt)
            #pragma unroll
            for (int e = 0; e < 4; ++e)
                Pb[(16 * w + lg * 4 + e) * 72 + nt * 16 + ls] = f2bf(pv[nt][e]);
        __syncthreads();

        // ---- phase 4: PV MFMA ----
        #pragma unroll
        for (int nt = 0; nt < 4; ++nt)
            #pragma unroll
            for (int e = 0; e < 4; ++e)
                acc_o[nt][e] *= fr[e];
        #pragma unroll
        for (int kki = 0; kki < 2; ++kki) {
            bf16x8 ap = *reinterpret_cast<const bf16x8*>(&Pb[(16 * w + ls) * 72 + kki * 32 + lg * 8]);
            #pragma unroll
            for (int nt = 0; nt < 4; ++nt) {
                bf16x8 bv = *reinterpret_cast<const bf16x8*>(&Vt[nt * 16 + ls][kki * 32 + lg * 8]);
                acc_o[nt] = __builtin_amdgcn_mfma_f32_16x16x32_bf16(ap, bv, acc_o[nt], 0, 0, 0);
            }
        }
        __syncthreads();
    }

    // epilogue
    #pragma unroll
    for (int nt = 0; nt < 4; ++nt) {
        int d = nt * 16 + ls;
        #pragma unroll
        for (int e = 0; e < 4; ++e) {
            int il = 16 * w + lg * 4 + e;
            float v = acc_o[nt][e] / l_r[e];
            attn[((size_t)b * S_LEN + i0 + il) * D_MODEL + h * DHEAD + d] = f2bf(v);
        }
    }
}

extern "C" void kernel_launch(void* const* d_in, const int* in_sizes, int n_in,
                              void* d_out, int out_size, void* d_ws, size_t ws_size,
                              hipStream_t stream) {
    const float* x    = (const float*)d_in[0];
    const float* pos  = (const float*)d_in[1];
    const float* Wq   = (const float*)d_in[2];
    const float* bq   = (const float*)d_in[3];
    const float* Wk   = (const float*)d_in[4];
    const float* bk   = (const float*)d_in[5];
    const float* Wv   = (const float*)d_in[6];
    const float* bv   = (const float*)d_in[7];
    const float* Wo   = (const float*)d_in[8];
    const float* bo   = (const float*)d_in[9];
    const float* Wkr  = (const float*)d_in[10];
    const float* bkr  = (const float*)d_in[11];
    const float* uu   = (const float*)d_in[12];
    const float* vv   = (const float*)d_in[13];

    char* w = (char*)d_ws;
    unsigned short* qT   = (unsigned short*)(w);                  // 8 MB
    unsigned short* kT   = (unsigned short*)(w + 8388608);        // 8 MB
    unsigned short* vTt  = (unsigned short*)(w + 16777216);       // 8 MB [bh][d][s]
    unsigned short* krT  = (unsigned short*)(w + 25165824);       // 4 MB
    unsigned short* attn = (unsigned short*)(w + 29360128);       // 8 MB
    float* EF            = (float*)(w + 37748736);                // 256 KB
    float* GH            = (float*)(w + 38010880);                // 128 KB
    unsigned short* xb   = (unsigned short*)(w + 38141952);       // 8 MB
    unsigned short* posb = (unsigned short*)(w + 46530560);       // 4 MB
    unsigned short* Wt   = (unsigned short*)(w + 50724864);       // 2 MB (reused)

    dim3 blk(256);
    dim3 gT(32, 32);
    dim3 gBig(8, 32);   // N/128, 4096/128
    dim3 gSm(8, 16);    // N/128, 2048/128

    convert_bf16<<<4096, blk, 0, stream>>>(x, xb, 1048576);
    convert_bf16<<<2048, blk, 0, stream>>>(pos, posb, 524288);

    convert_transpose<<<gT, blk, 0, stream>>>(Wq, Wt);
    gemm_mfma<1><<<gBig, blk, 0, stream>>>(xb, Wt, bq, qT, 4096);
    convert_transpose<<<gT, blk, 0, stream>>>(Wk, Wt);
    gemm_mfma<1><<<gBig, blk, 0, stream>>>(xb, Wt, bk, kT, 4096);
    convert_transpose<<<gT, blk, 0, stream>>>(Wv, Wt);
    gemm_mfma<3><<<gBig, blk, 0, stream>>>(xb, Wt, bv, vTt, 4096);
    convert_transpose<<<gT, blk, 0, stream>>>(Wkr, Wt);
    gemm_mfma<2><<<gSm, blk, 0, stream>>>(posb, Wt, bkr, krT, 2048);

    ef_gh_kernel<<<(NB * NH * S_LEN) / 256, blk, 0, stream>>>(uu, kT, EF, NB * NH * S_LEN);
    ef_gh_kernel<<<(NH * S_LEN) / 256, blk, 0, stream>>>(vv, krT, GH, NH * S_LEN);

    flash_mfma<<<NB * NH * (S_LEN / 64), blk, 0, stream>>>(qT, kT, vTt, krT, EF, GH, attn);

    convert_transpose<<<gT, blk, 0, stream>>>(Wo, Wt);
    gemm_mfma<0><<<gBig, blk, 0, stream>>>(attn, Wt, bo, (float*)d_out, 4096);
}